// Round 1
// baseline (488.772 us; speedup 1.0000x reference)
//
#include <hip/hip_runtime.h>
#include <hip/hip_bf16.h>

// Problem constants (from reference)
#define NNODES 10000
#define NEDGES 320000
#define INF_   1280
#define HID_   128
#define HEADS_ 4
#define OUTF_  500
#define HC_    512          // HEADS_*HID_
#define NEG_SLOPE 0.2f
#define BN_EPS 1e-5f

typedef __attribute__((ext_vector_type(8))) short short8x;
typedef __attribute__((ext_vector_type(4))) float f32x4;
typedef unsigned short ushort_t;
typedef unsigned int uint_t;

__device__ __forceinline__ ushort_t f2bf(float f) {
    uint_t u = __float_as_uint(f);
    u = (u + 0x7fffu + ((u >> 16) & 1u)) >> 16;   // round-to-nearest-even
    return (ushort_t)u;
}
__device__ __forceinline__ float bf_lo(uint_t p) { return __uint_as_float(p << 16); }
__device__ __forceinline__ float bf_hi(uint_t p) { return __uint_as_float(p & 0xffff0000u); }
__device__ __forceinline__ float lrelu(float x) { return (x >= 0.f) ? x : NEG_SLOPE * x; }
__device__ __forceinline__ uint_t pack_bf16_rn(float a, float b) {
    __hip_bfloat162 h = __float22bfloat162_rn(make_float2(a, b));  // hw packed cvt, RNE
    return *(uint_t*)&h;
}

// async global->LDS staging, 16B per lane (guide §5: compiler never auto-emits this)
typedef __attribute__((address_space(1))) void gvoid_t;
typedef __attribute__((address_space(3))) void lvoid_t;
#define GL16(gp, lp) __builtin_amdgcn_global_load_lds((gvoid_t*)(gp), (lvoid_t*)(lp), 16, 0, 0)

// ---------------------------------------------------------------------------
// utility
// ---------------------------------------------------------------------------
__global__ void zero_kernel(float* __restrict__ p, size_t n) {
    size_t i = (size_t)blockIdx.x * blockDim.x + threadIdx.x;
    size_t stride = (size_t)gridDim.x * blockDim.x;
    for (; i < n; i += stride) p[i] = 0.0f;
}

// one kernel: x->bf16 (vectorized) + 3 weight transposes
#define CVX (NNODES * INF_ / 4)        // 3,200,000 float4 chunks of x
#define CN1 (HC_ * INF_)
#define CN2 (HC_ * HC_)
#define CN3 (HC_ * HC_)                // Wt3 (padded rows)
__global__ void convall_kernel(const float* __restrict__ x,
                               const float* __restrict__ W1,
                               const float* __restrict__ W2,
                               const float* __restrict__ W3,
                               ushort_t* __restrict__ x_bf,
                               ushort_t* __restrict__ Wt1,
                               ushort_t* __restrict__ Wt2,
                               ushort_t* __restrict__ Wt3) {
    int i = blockIdx.x * blockDim.x + threadIdx.x;
    if (i < CVX) {
        float4 v = ((const float4*)x)[i];
        ((uint2*)x_bf)[i] = make_uint2(pack_bf16_rn(v.x, v.y), pack_bf16_rn(v.z, v.w));
    } else if (i < CVX + CN1) {
        int j = i - CVX;
        int n = j / INF_, k = j - n * INF_;
        Wt1[j] = f2bf(W1[(size_t)k * HC_ + n]);
    } else if (i < CVX + CN1 + CN2) {
        int j = i - CVX - CN1;
        int n = j / HC_, k = j - n * HC_;
        Wt2[j] = f2bf(W2[(size_t)k * HC_ + n]);
    } else if (i < CVX + CN1 + CN2 + CN3) {
        int j = i - CVX - CN1 - CN2;
        int n = j / HC_, k = j - n * HC_;
        Wt3[j] = (n < OUTF_) ? f2bf(W3[(size_t)k * OUTF_ + n]) : (ushort_t)0;
    }
}

// ---------------------------------------------------------------------------
// CSR build (by destination)
// ---------------------------------------------------------------------------
__global__ void count_kernel(const int* __restrict__ dst, int* __restrict__ counts, int E) {
    int e = blockIdx.x * blockDim.x + threadIdx.x;
    if (e < E) atomicAdd(&counts[dst[e]], 1);
}

__global__ __launch_bounds__(256) void scan1_kernel(const int* __restrict__ counts,
                                                    int* __restrict__ offsets,
                                                    int* __restrict__ bsum, int n) {
    __shared__ int tmp[256];
    int b = blockIdx.x, t = threadIdx.x;
    int i = b * 256 + t;
    int v = (i < n) ? counts[i] : 0;
    tmp[t] = v;
    __syncthreads();
    for (int off = 1; off < 256; off <<= 1) {
        int u = (t >= off) ? tmp[t - off] : 0;
        __syncthreads();
        tmp[t] += u;
        __syncthreads();
    }
    if (i < n) offsets[i] = tmp[t] - v;
    if (t == 255) bsum[b] = tmp[t];
}

__global__ __launch_bounds__(256) void scan3b_kernel(int* __restrict__ offsets,
                                                     int* __restrict__ cursor,
                                                     const int* __restrict__ bsum,
                                                     int nb, int n) {
    __shared__ int base_sh, tot_sh;
    int b = blockIdx.x, t = threadIdx.x;
    if (t == 0) {
        int acc = 0, tot = 0;
        for (int k = 0; k < nb; ++k) { if (k < b) acc += bsum[k]; tot += bsum[k]; }
        base_sh = acc; tot_sh = tot;
    }
    __syncthreads();
    int i = b * 256 + t;
    if (i < n) {
        int v = offsets[i] + base_sh;
        offsets[i] = v;
        cursor[i] = v;
    }
    if (b == nb - 1 && t == 0) offsets[n] = tot_sh;
}

__global__ void scatter_kernel(const int* __restrict__ src, const int* __restrict__ dst,
                               int* __restrict__ cursor, int* __restrict__ esrc, int E) {
    int e = blockIdx.x * blockDim.x + threadIdx.x;
    if (e < E) {
        int p = atomicAdd(&cursor[dst[e]], 1);
        esrc[p] = src[e];
    }
}

// ---------------------------------------------------------------------------
// bf16 MFMA GEMM — m97 structure: 128x128 tile, BK=32, single LDS buffer,
// global_load_lds width-16 staging (4 issues/thread/K-step), 2 barriers/K-step.
// 1-D grid with bijective XCD chunk swizzle (m204) so the 4 N-tile blocks
// sharing an A panel land on the same XCD's L2.
// Fragment/acc layout identical to the previously verified 64x128 kernel.
// ---------------------------------------------------------------------------
__global__ __launch_bounds__(256) void gemm_kernel(
    const ushort_t* __restrict__ A,    // [M][K] bf16
    const ushort_t* __restrict__ Bt,   // [512][K] bf16 (transposed, padded)
    ushort_t* __restrict__ Cb,         // [M][512] bf16
    int M, int K)
{
    __shared__ __align__(16) ushort_t As[128 * 32];   // 8 KB, linear (glds needs it)
    __shared__ __align__(16) ushort_t Bs[128 * 32];   // 8 KB

    // bijective XCD chunk swizzle: physical block p sits on XCD p%8; give each
    // XCD a CONTIGUOUS range of logical tiles (same-A blocks are adjacent).
    int nwg  = gridDim.x;
    int orig = blockIdx.x;
    int q = nwg >> 3, r = nwg & 7;
    int xcd = orig & 7;
    int lid = (xcd < r ? xcd * (q + 1) : r * (q + 1) + (xcd - r) * q) + (orig >> 3);
    int by = lid >> 2;            // M-tile (N/128 == 4 tiles, fastest-varying)
    int bx = lid & 3;
    int m0 = by * 128;
    int n0 = bx * 128;

    int tid  = threadIdx.x;
    int lane = tid & 63;
    int w    = tid >> 6;
    int wm   = (w & 1) * 64;       // wave m-offset (wave tile 64x64)
    int wn   = (w >> 1) * 64;      // wave n-offset
    int quad = lane >> 4;
    int c16  = lane & 15;

    f32x4 acc[4][4];
#pragma unroll
    for (int i = 0; i < 4; ++i)
#pragma unroll
        for (int j = 0; j < 4; ++j)
#pragma unroll
            for (int t = 0; t < 4; ++t) acc[i][j][t] = 0.0f;

    // staging: thread stages 16B at linear elem tid*8 (+2048 for second half).
    // row = tid>>2, col = (tid&3)*8 — lane-contiguous per wave (glds-compatible).
    int srow = tid >> 2;
    int scol = (tid & 3) * 8;
    int ga0 = m0 + srow;        if (ga0 > M - 1) ga0 = M - 1;
    int ga1 = m0 + 64 + srow;   if (ga1 > M - 1) ga1 = M - 1;
    const ushort_t* ap0 = A  + (size_t)ga0 * K + scol;
    const ushort_t* ap1 = A  + (size_t)ga1 * K + scol;
    const ushort_t* bp0 = Bt + (size_t)(n0 + srow) * K + scol;
    const ushort_t* bp1 = Bt + (size_t)(n0 + 64 + srow) * K + scol;
    ushort_t* lA0 = &As[tid * 8];
    ushort_t* lA1 = &As[2048 + tid * 8];
    ushort_t* lB0 = &Bs[tid * 8];
    ushort_t* lB1 = &Bs[2048 + tid * 8];

    for (int k0 = 0; k0 < K; k0 += 32) {
        GL16(ap0 + k0, lA0);
        GL16(ap1 + k0, lA1);
        GL16(bp0 + k0, lB0);
        GL16(bp1 + k0, lB1);
        __syncthreads();                       // drains vmcnt(0): tiles in LDS

        short8x af[4], bf[4];
#pragma unroll
        for (int mt = 0; mt < 4; ++mt)
            af[mt] = *(const short8x*)&As[(wm + mt * 16 + c16) * 32 + quad * 8];
#pragma unroll
        for (int nt = 0; nt < 4; ++nt)
            bf[nt] = *(const short8x*)&Bs[(wn + nt * 16 + c16) * 32 + quad * 8];

#pragma unroll
        for (int mt = 0; mt < 4; ++mt)
#pragma unroll
            for (int nt = 0; nt < 4; ++nt)
                acc[mt][nt] = __builtin_amdgcn_mfma_f32_16x16x32_bf16(af[mt], bf[nt], acc[mt][nt], 0, 0, 0);
        __syncthreads();                       // reads done before next overwrite
    }

#pragma unroll
    for (int mt = 0; mt < 4; ++mt) {
#pragma unroll
        for (int t = 0; t < 4; ++t) {
            int row = m0 + wm + mt * 16 + quad * 4 + t;
            if (row < M) {
#pragma unroll
                for (int nt = 0; nt < 4; ++nt) {
                    int col = n0 + wn + nt * 16 + c16;
                    Cb[(size_t)row * 512 + col] = f2bf(acc[mt][nt][t]);
                }
            }
        }
    }
}

// ---------------------------------------------------------------------------
// logits: one wave per node (4 nodes/block). Lane l owns channels [8l, 8l+8).
// ---------------------------------------------------------------------------
template<int H>
__global__ __launch_bounds__(256) void logits_kernel(
    const uint4* __restrict__ xpb4,    // [node][64]
    const float* __restrict__ aS, const float* __restrict__ aD,
    float* __restrict__ s_log, float* __restrict__ d_log, int OUTC)
{
    int node = blockIdx.x * 4 + (threadIdx.x >> 6);
    if (node >= NNODES) return;
    int lane = threadIdx.x & 63;
    uint4 p = xpb4[(size_t)node * 64 + lane];
    float xv[8] = {bf_lo(p.x), bf_hi(p.x), bf_lo(p.y), bf_hi(p.y),
                   bf_lo(p.z), bf_hi(p.z), bf_lo(p.w), bf_hi(p.w)};
    int cbase = lane * 8;
    float sv = 0.f, dv = 0.f;
    if (cbase + 7 < OUTC) {
        float4 a0 = ((const float4*)aS)[lane * 2];
        float4 a1 = ((const float4*)aS)[lane * 2 + 1];
        float4 b0 = ((const float4*)aD)[lane * 2];
        float4 b1 = ((const float4*)aD)[lane * 2 + 1];
        sv = xv[0]*a0.x + xv[1]*a0.y + xv[2]*a0.z + xv[3]*a0.w
           + xv[4]*a1.x + xv[5]*a1.y + xv[6]*a1.z + xv[7]*a1.w;
        dv = xv[0]*b0.x + xv[1]*b0.y + xv[2]*b0.z + xv[3]*b0.w
           + xv[4]*b1.x + xv[5]*b1.y + xv[6]*b1.z + xv[7]*b1.w;
    } else {
#pragma unroll
        for (int k = 0; k < 8; ++k) {
            int c = cbase + k;
            if (c < OUTC) { sv += xv[k] * aS[c]; dv += xv[k] * aD[c]; }
        }
    }
    int grp = (H == 4) ? 16 : 64;
    for (int off = 1; off < grp; off <<= 1) {
        sv += __shfl_xor(sv, off);
        dv += __shfl_xor(dv, off);
    }
    if ((lane & (grp - 1)) == 0) {
        int h = (H == 4) ? (lane >> 4) : 0;
        s_log[node * H + h] = sv;
        d_log[node * H + h] = dv;
    }
}

// ---------------------------------------------------------------------------
// edge softmax — SINGLE PASS. Softmax is shift-invariant; shift by the
// self-loop logit selfe[h] (known before any edge is read) instead of the
// true max: exp(e - selfe)/Σ is mathematically identical, logits are O(10)
// so exp stays far inside f32 range. Kills the whole max pass + butterfly;
// wself becomes exactly 1.
// ---------------------------------------------------------------------------
template<int H>
__global__ __launch_bounds__(256) void edge_softmax_kernel(
    const float* __restrict__ s, const float* __restrict__ dlog,
    const int* __restrict__ offsets, const int* __restrict__ esrc,
    float* __restrict__ ew, float* __restrict__ wself, float* __restrict__ zinv)
{
    int node = blockIdx.x * 4 + (threadIdx.x >> 6);
    if (node >= NNODES) return;
    int lane = threadIdx.x & 63;
    int e0 = offsets[node], e1 = offsets[node + 1];

    float dh[H], c0[H], zh[H];
#pragma unroll
    for (int h = 0; h < H; ++h) {
        dh[h] = dlog[node * H + h];
        c0[h] = lrelu(s[node * H + h] + dh[h]);   // self-loop logit = shift
        zh[h] = 0.f;
    }
    for (int j = e0 + lane; j < e1; j += 64) {
        int src = esrc[j];
        if (H == 4) {
            float4 sv = ((const float4*)s)[src];
            float w0 = __expf(lrelu(sv.x + dh[0]) - c0[0]);
            float w1 = __expf(lrelu(sv.y + dh[1]) - c0[1]);
            float w2 = __expf(lrelu(sv.z + dh[2]) - c0[2]);
            float w3 = __expf(lrelu(sv.w + dh[3]) - c0[3]);
            ((float4*)ew)[j] = make_float4(w0, w1, w2, w3);
            zh[0] += w0; zh[1] += w1; zh[2] += w2; zh[3] += w3;
        } else {
            float w0 = __expf(lrelu(s[src] + dh[0]) - c0[0]);
            ew[j] = w0;
            zh[0] += w0;
        }
    }
#pragma unroll
    for (int h = 0; h < H; ++h)
        for (int off = 32; off > 0; off >>= 1)
            zh[h] += __shfl_xor(zh[h], off);

    if (lane == 0) {
#pragma unroll
        for (int h = 0; h < H; ++h) {
            wself[node * H + h] = 1.0f;          // exp(selfe - selfe)
            zinv[node * H + h] = 1.0f / (zh[h] + 1.0f);
        }
    }
}

// ---------------------------------------------------------------------------
// SLICED gather (R13, proven): slice pinned per XCD pair, 2.56 MB L2-resident.
// ---------------------------------------------------------------------------
__device__ __forceinline__ void acc8(float* acc, uint4 q, float w) {
    acc[0] += w * bf_lo(q.x); acc[1] += w * bf_hi(q.x);
    acc[2] += w * bf_lo(q.y); acc[3] += w * bf_hi(q.y);
    acc[4] += w * bf_lo(q.z); acc[5] += w * bf_hi(q.z);
    acc[6] += w * bf_lo(q.w); acc[7] += w * bf_hi(q.w);
}

template<int H>
__global__ __launch_bounds__(256) void gather_sliced_kernel(
    const uint4* __restrict__ xpb4,     // [node][64]
    const int* __restrict__ offsets, const int* __restrict__ esrc,
    const float* __restrict__ ew,       // [E][H]
    const float* __restrict__ wself,    // [node][H]
    const float* __restrict__ zinv,     // [node][H]
    const float* __restrict__ bias,     // [OUTC]
    float* __restrict__ out,            // [node][ldo]
    int OUTC, int ldo)
{
    int id = blockIdx.x;
    int xcd = id & 7;
    int slice = xcd >> 1;                       // 0..3 — pinned per XCD pair
    int sub2 = xcd & 1;
    int wv = threadIdx.x >> 6;
    int node = (id >> 3) * 8 + sub2 * 4 + wv;
    if (node >= NNODES) return;
    int lane = threadIdx.x & 63;
    int esub = lane >> 4;                       // edge subgroup 0..3
    int l16 = lane & 15;
    int h = (H == 4) ? slice : 0;
    int rowoff = slice * 16 + l16;              // uint4 index within 64-wide row

    float acc[8];
    if (esub == 0) {
        float ws = wself[node * H + h];
        uint4 p = xpb4[(size_t)node * 64 + rowoff];
        acc[0] = ws * bf_lo(p.x); acc[1] = ws * bf_hi(p.x);
        acc[2] = ws * bf_lo(p.y); acc[3] = ws * bf_hi(p.y);
        acc[4] = ws * bf_lo(p.z); acc[5] = ws * bf_hi(p.z);
        acc[6] = ws * bf_lo(p.w); acc[7] = ws * bf_hi(p.w);
    } else {
#pragma unroll
        for (int k = 0; k < 8; ++k) acc[k] = 0.f;
    }

    int e0 = offsets[node], e1 = offsets[node + 1];
    int j = e0 + esub;
    for (; j + 12 < e1; j += 16) {
        int s0 = esrc[j], s1 = esrc[j + 4], s2 = esrc[j + 8], s3 = esrc[j + 12];
        float w0 = ew[(size_t)j * H + h];
        float w1 = ew[(size_t)(j + 4) * H + h];
        float w2 = ew[(size_t)(j + 8) * H + h];
        float w3 = ew[(size_t)(j + 12) * H + h];
        uint4 q0 = xpb4[(size_t)s0 * 64 + rowoff];
        uint4 q1 = xpb4[(size_t)s1 * 64 + rowoff];
        uint4 q2 = xpb4[(size_t)s2 * 64 + rowoff];
        uint4 q3 = xpb4[(size_t)s3 * 64 + rowoff];
        acc8(acc, q0, w0);
        acc8(acc, q1, w1);
        acc8(acc, q2, w2);
        acc8(acc, q3, w3);
    }
    for (; j < e1; j += 4) {
        int s0 = esrc[j];
        float w0 = ew[(size_t)j * H + h];
        uint4 q0 = xpb4[(size_t)s0 * 64 + rowoff];
        acc8(acc, q0, w0);
    }

    // combine the 4 edge subgroups
#pragma unroll
    for (int k = 0; k < 8; ++k) {
        acc[k] += __shfl_xor(acc[k], 16);
        acc[k] += __shfl_xor(acc[k], 32);
    }

    if (esub == 0) {
        float zi = zinv[node * H + h];
        int cbase = slice * 128 + l16 * 8;
        size_t ob = (size_t)node * ldo + cbase;
        if (cbase + 7 < OUTC) {
            float4 o0 = make_float4(acc[0] * zi + bias[cbase + 0], acc[1] * zi + bias[cbase + 1],
                                    acc[2] * zi + bias[cbase + 2], acc[3] * zi + bias[cbase + 3]);
            float4 o1 = make_float4(acc[4] * zi + bias[cbase + 4], acc[5] * zi + bias[cbase + 5],
                                    acc[6] * zi + bias[cbase + 6], acc[7] * zi + bias[cbase + 7]);
            *(float4*)(out + ob) = o0;
            *(float4*)(out + ob + 4) = o1;
        } else {
#pragma unroll
            for (int k = 0; k < 8; ++k) {
                int c = cbase + k;
                if (c < OUTC) out[ob + k] = acc[k] * zi + bias[c];
            }
        }
    }
}

// ---------------------------------------------------------------------------
// BatchNorm: stats (64-block partials) -> tiny finalize -> wide apply+pack.
// ---------------------------------------------------------------------------
__global__ __launch_bounds__(512) void bn_stats_kernel(const float* __restrict__ h,
                                                       float* __restrict__ psum,
                                                       float* __restrict__ psumsq) {
    int c = threadIdx.x;  // 512
    int b = blockIdx.x;   // 64
    float sm = 0.f, sq = 0.f;
    for (int r = b; r < NNODES; r += 64) {
        float v = h[(size_t)r * 512 + c];
        sm += v;
        sq += v * v;
    }
    psum[b * 512 + c] = sm;
    psumsq[b * 512 + c] = sq;
}

__global__ __launch_bounds__(512) void bn_finalize_kernel(const float* __restrict__ psum,
                                                          const float* __restrict__ psumsq,
                                                          const float* __restrict__ gamma,
                                                          const float* __restrict__ beta,
                                                          float* __restrict__ scale,
                                                          float* __restrict__ shift) {
    int c = threadIdx.x;
    float sm = 0.f, sq = 0.f;
    for (int b = 0; b < 64; ++b) {
        sm += psum[b * 512 + c];
        sq += psumsq[b * 512 + c];
    }
    const float invN = 1.0f / (float)NNODES;
    float mu = sm * invN;
    float var = sq * invN - mu * mu;
    float sc = gamma[c] * rsqrtf(var + BN_EPS);
    scale[c] = sc;
    shift[c] = beta[c] - mu * sc;
}

__global__ __launch_bounds__(256) void bn_apply_kernel(const float* __restrict__ h,
                                                       const float* __restrict__ scale,
                                                       const float* __restrict__ shift,
                                                       uint_t* __restrict__ hbf) {
    int t = threadIdx.x, b = blockIdx.x;   // grid = 256
    int c0 = t * 2, c1 = c0 + 1;
    float sc0 = scale[c0], sc1 = scale[c1];
    float sh0 = shift[c0], sh1 = shift[c1];
    for (int r = b; r < NNODES; r += 256) {
        float2 hv = ((const float2*)(h + (size_t)r * 512))[t];
        float v0 = hv.x * sc0 + sh0;
        float v1 = hv.y * sc1 + sh1;
        v0 = (v0 > 0.f) ? v0 : (__expf(v0) - 1.0f);
        v1 = (v1 > 0.f) ? v1 : (__expf(v1) - 1.0f);
        hbf[r * 256 + t] = ((uint_t)f2bf(v1) << 16) | (uint_t)f2bf(v0);
    }
}

// ---------------------------------------------------------------------------
// launch — 24 dispatches
// ---------------------------------------------------------------------------
extern "C" void kernel_launch(void* const* d_in, const int* in_sizes, int n_in,
                              void* d_out, int out_size, void* d_ws, size_t ws_size,
                              hipStream_t stream) {
    const float* x      = (const float*)d_in[0];
    const int*   ei     = (const int*)d_in[1];
    const float* W1     = (const float*)d_in[2];
    const float* a_src1 = (const float*)d_in[3];
    const float* a_dst1 = (const float*)d_in[4];
    const float* b1     = (const float*)d_in[5];
    const float* g1     = (const float*)d_in[6];
    const float* be1    = (const float*)d_in[7];
    const float* W2     = (const float*)d_in[8];
    const float* a_src2 = (const float*)d_in[9];
    const float* a_dst2 = (const float*)d_in[10];
    const float* b2     = (const float*)d_in[11];
    const float* g2     = (const float*)d_in[12];
    const float* be2    = (const float*)d_in[13];
    const float* W3     = (const float*)d_in[14];
    const float* a_src3 = (const float*)d_in[15];
    const float* a_dst3 = (const float*)d_in[16];
    const float* b3     = (const float*)d_in[17];
    float* out = (float*)d_out;

    const int* e_src = ei;           // edge_index[0]
    const int* e_dst = ei + NEDGES;  // edge_index[1]

    // ---- workspace layout ----
    char* w = (char*)d_ws;
    ushort_t* x_bf = (ushort_t*)w;
    float*    hbuf = (float*)w;                               // alias after L1 GEMM
    float*    ew   = (float*)(w + (size_t)NNODES * HC_ * sizeof(float));  // tail 5.12 MB
    w += (size_t)NNODES * INF_ * sizeof(ushort_t);            // 25.6 MB
    uint_t* xpb = (uint_t*)w;  w += (size_t)NNODES * HC_ * sizeof(ushort_t);
    uint_t* hbf = (uint_t*)w;  w += (size_t)NNODES * HC_ * sizeof(ushort_t);
    ushort_t* Wt1 = (ushort_t*)w; w += (size_t)HC_ * INF_ * sizeof(ushort_t);
    ushort_t* Wt2 = (ushort_t*)w; w += (size_t)HC_ * HC_ * sizeof(ushort_t);
    ushort_t* Wt3 = (ushort_t*)w; w += (size_t)HC_ * HC_ * sizeof(ushort_t);
    int* counts  = (int*)w;    w += NNODES * sizeof(int);
    float* s_log = (float*)w;  w += NNODES * HEADS_ * sizeof(float);
    float* d_log = (float*)w;  w += NNODES * HEADS_ * sizeof(float);
    float* wself = (float*)w;  w += NNODES * HEADS_ * sizeof(float);
    float* zinv  = (float*)w;  w += NNODES * HEADS_ * sizeof(float);
    float* bnscale = (float*)w; w += HC_ * sizeof(float);
    float* bnshift = (float*)w; w += HC_ * sizeof(float);
    float* psum  = (float*)w;  w += 64 * HC_ * sizeof(float);
    float* psumsq= (float*)w;  w += 64 * HC_ * sizeof(float);
    int* offsets = (int*)w;    w += (NNODES + 1) * sizeof(int);
    int* cursor  = (int*)w;    w += NNODES * sizeof(int);
    int* esrc    = (int*)w;    w += NEDGES * sizeof(int);
    int* bsum    = (int*)w;    w += 64 * sizeof(int);

    const int ggBlocks = ((NNODES + 127) / 128) * (HC_ / 128);  // 79*4 = 316
    const int lgGrid = (NNODES + 3) / 4;             // 2500 (logits / softmax)
    const int gaGrid = ((NNODES + 7) / 8) * 8;       // 10000 (sliced gather)
    const int scanBlocks = (NNODES + 255) / 256;     // 40

    zero_kernel<<<32, 256, 0, stream>>>((float*)counts, NNODES);
    count_kernel<<<(NEDGES + 255) / 256, 256, 0, stream>>>(e_dst, counts, NEDGES);
    scan1_kernel<<<scanBlocks, 256, 0, stream>>>(counts, offsets, bsum, NNODES);
    scan3b_kernel<<<scanBlocks, 256, 0, stream>>>(offsets, cursor, bsum, scanBlocks, NNODES);
    scatter_kernel<<<(NEDGES + 255) / 256, 256, 0, stream>>>(e_src, e_dst, cursor, esrc, NEDGES);
    {
        int TOT = CVX + CN1 + CN2 + CN3;
        convall_kernel<<<(TOT + 255) / 256, 256, 0, stream>>>(x, W1, W2, W3, x_bf, Wt1, Wt2, Wt3);
    }

    // ---- Layer 1 ----
    gemm_kernel<<<ggBlocks, 256, 0, stream>>>(x_bf, Wt1, (ushort_t*)xpb, NNODES, INF_);
    logits_kernel<HEADS_><<<lgGrid, 256, 0, stream>>>((const uint4*)xpb, a_src1, a_dst1, s_log, d_log, HC_);
    edge_softmax_kernel<HEADS_><<<lgGrid, 256, 0, stream>>>(s_log, d_log, offsets, esrc, ew, wself, zinv);
    gather_sliced_kernel<HEADS_><<<gaGrid, 256, 0, stream>>>((const uint4*)xpb, offsets, esrc,
        ew, wself, zinv, b1, hbuf, HC_, HC_);
    bn_stats_kernel<<<64, 512, 0, stream>>>(hbuf, psum, psumsq);
    bn_finalize_kernel<<<1, 512, 0, stream>>>(psum, psumsq, g1, be1, bnscale, bnshift);
    bn_apply_kernel<<<256, 256, 0, stream>>>(hbuf, bnscale, bnshift, hbf);

    // ---- Layer 2 ----
    gemm_kernel<<<ggBlocks, 256, 0, stream>>>((const ushort_t*)hbf, Wt2, (ushort_t*)xpb, NNODES, HC_);
    logits_kernel<HEADS_><<<lgGrid, 256, 0, stream>>>((const uint4*)xpb, a_src2, a_dst2, s_log, d_log, HC_);
    edge_softmax_kernel<HEADS_><<<lgGrid, 256, 0, stream>>>(s_log, d_log, offsets, esrc, ew, wself, zinv);
    gather_sliced_kernel<HEADS_><<<gaGrid, 256, 0, stream>>>((const uint4*)xpb, offsets, esrc,
        ew, wself, zinv, b2, hbuf, HC_, HC_);
    bn_stats_kernel<<<64, 512, 0, stream>>>(hbuf, psum, psumsq);
    bn_finalize_kernel<<<1, 512, 0, stream>>>(psum, psumsq, g2, be2, bnscale, bnshift);
    bn_apply_kernel<<<256, 256, 0, stream>>>(hbuf, bnscale, bnshift, hbf);

    // ---- Layer 3 (H=1, N=500) ----
    gemm_kernel<<<ggBlocks, 256, 0, stream>>>((const ushort_t*)hbf, Wt3, (ushort_t*)xpb, NNODES, HC_);
    logits_kernel<1><<<lgGrid, 256, 0, stream>>>((const uint4*)xpb, a_src3, a_dst3, s_log, d_log, OUTF_);
    edge_softmax_kernel<1><<<lgGrid, 256, 0, stream>>>(s_log, d_log, offsets, esrc, ew, wself, zinv);
    gather_sliced_kernel<1><<<gaGrid, 256, 0, stream>>>((const uint4*)xpb, offsets, esrc,
        ew, wself, zinv, b3, out, OUTF_, OUTF_);
}

// Round 2
// 464.428 us; speedup vs baseline: 1.0524x; 1.0524x over previous
//
#include <hip/hip_runtime.h>
#include <hip/hip_bf16.h>

// Problem constants (from reference)
#define NNODES 10000
#define NEDGES 320000
#define INF_   1280
#define HID_   128
#define HEADS_ 4
#define OUTF_  500
#define HC_    512          // HEADS_*HID_
#define NEG_SLOPE 0.2f
#define BN_EPS 1e-5f

typedef __attribute__((ext_vector_type(8))) short short8x;
typedef __attribute__((ext_vector_type(4))) float f32x4;
typedef unsigned short ushort_t;
typedef unsigned int uint_t;

__device__ __forceinline__ ushort_t f2bf(float f) {
    uint_t u = __float_as_uint(f);
    u = (u + 0x7fffu + ((u >> 16) & 1u)) >> 16;   // round-to-nearest-even
    return (ushort_t)u;
}
__device__ __forceinline__ float bf_lo(uint_t p) { return __uint_as_float(p << 16); }
__device__ __forceinline__ float bf_hi(uint_t p) { return __uint_as_float(p & 0xffff0000u); }
__device__ __forceinline__ float lrelu(float x) { return (x >= 0.f) ? x : NEG_SLOPE * x; }
__device__ __forceinline__ uint_t pack_bf16_rn(float a, float b) {
    __hip_bfloat162 h = __float22bfloat162_rn(make_float2(a, b));  // hw packed cvt, RNE
    return *(uint_t*)&h;
}

// ---------------------------------------------------------------------------
// utility
// ---------------------------------------------------------------------------
__global__ void zero_kernel(float* __restrict__ p, size_t n) {
    size_t i = (size_t)blockIdx.x * blockDim.x + threadIdx.x;
    size_t stride = (size_t)gridDim.x * blockDim.x;
    for (; i < n; i += stride) p[i] = 0.0f;
}

// one kernel: x->bf16 (vectorized) + 3 weight transposes
#define CVX (NNODES * INF_ / 4)        // 3,200,000 float4 chunks of x
#define CN1 (HC_ * INF_)
#define CN2 (HC_ * HC_)
#define CN3 (HC_ * HC_)                // Wt3 (padded rows)
__global__ void convall_kernel(const float* __restrict__ x,
                               const float* __restrict__ W1,
                               const float* __restrict__ W2,
                               const float* __restrict__ W3,
                               ushort_t* __restrict__ x_bf,
                               ushort_t* __restrict__ Wt1,
                               ushort_t* __restrict__ Wt2,
                               ushort_t* __restrict__ Wt3) {
    int i = blockIdx.x * blockDim.x + threadIdx.x;
    if (i < CVX) {
        float4 v = ((const float4*)x)[i];
        ((uint2*)x_bf)[i] = make_uint2(pack_bf16_rn(v.x, v.y), pack_bf16_rn(v.z, v.w));
    } else if (i < CVX + CN1) {
        int j = i - CVX;
        int n = j / INF_, k = j - n * INF_;
        Wt1[j] = f2bf(W1[(size_t)k * HC_ + n]);
    } else if (i < CVX + CN1 + CN2) {
        int j = i - CVX - CN1;
        int n = j / HC_, k = j - n * HC_;
        Wt2[j] = f2bf(W2[(size_t)k * HC_ + n]);
    } else if (i < CVX + CN1 + CN2 + CN3) {
        int j = i - CVX - CN1 - CN2;
        int n = j / HC_, k = j - n * HC_;
        Wt3[j] = (n < OUTF_) ? f2bf(W3[(size_t)k * OUTF_ + n]) : (ushort_t)0;
    }
}

// ---------------------------------------------------------------------------
// CSR build (by destination)
// ---------------------------------------------------------------------------
__global__ void count_kernel(const int* __restrict__ dst, int* __restrict__ counts, int E) {
    int e = blockIdx.x * blockDim.x + threadIdx.x;
    if (e < E) atomicAdd(&counts[dst[e]], 1);
}

__global__ __launch_bounds__(256) void scan1_kernel(const int* __restrict__ counts,
                                                    int* __restrict__ offsets,
                                                    int* __restrict__ bsum, int n) {
    __shared__ int tmp[256];
    int b = blockIdx.x, t = threadIdx.x;
    int i = b * 256 + t;
    int v = (i < n) ? counts[i] : 0;
    tmp[t] = v;
    __syncthreads();
    for (int off = 1; off < 256; off <<= 1) {
        int u = (t >= off) ? tmp[t - off] : 0;
        __syncthreads();
        tmp[t] += u;
        __syncthreads();
    }
    if (i < n) offsets[i] = tmp[t] - v;
    if (t == 255) bsum[b] = tmp[t];
}

__global__ __launch_bounds__(256) void scan3b_kernel(int* __restrict__ offsets,
                                                     int* __restrict__ cursor,
                                                     const int* __restrict__ bsum,
                                                     int nb, int n) {
    __shared__ int base_sh, tot_sh;
    int b = blockIdx.x, t = threadIdx.x;
    if (t == 0) {
        int acc = 0, tot = 0;
        for (int k = 0; k < nb; ++k) { if (k < b) acc += bsum[k]; tot += bsum[k]; }
        base_sh = acc; tot_sh = tot;
    }
    __syncthreads();
    int i = b * 256 + t;
    if (i < n) {
        int v = offsets[i] + base_sh;
        offsets[i] = v;
        cursor[i] = v;
    }
    if (b == nb - 1 && t == 0) offsets[n] = tot_sh;
}

__global__ void scatter_kernel(const int* __restrict__ src, const int* __restrict__ dst,
                               int* __restrict__ cursor, int* __restrict__ esrc, int E) {
    int e = blockIdx.x * blockDim.x + threadIdx.x;
    if (e < E) {
        int p = atomicAdd(&cursor[dst[e]], 1);
        esrc[p] = src[e];
    }
}

// ---------------------------------------------------------------------------
// bf16 MFMA GEMM — 64(M) x 128(N) tile, BK=32, plain 2-D grid,
// REGISTER-PREFETCH pipeline (proven 486.6 µs structure): iter k+1's global
// loads issue right after iter k's LDS reads so the ~600-cyc global latency
// overlaps MFMA+barrier. At this shape (628 blocks) this beats the m97
// 128x128 single-buffer structure (R0->R1: net-neutral => GEMM regressed).
// ---------------------------------------------------------------------------
#define LDT 40

__global__ __launch_bounds__(256) void gemm_kernel(
    const ushort_t* __restrict__ A,    // [M][K] bf16
    const ushort_t* __restrict__ Bt,   // [512][K] bf16 (transposed, padded)
    ushort_t* __restrict__ Cb,         // [M][512] bf16
    int M, int K)
{
    __shared__ __align__(16) ushort_t As[64 * LDT];
    __shared__ __align__(16) ushort_t Bs[128 * LDT];

    int m0 = blockIdx.y * 64;
    int n0 = blockIdx.x * 128;

    int tid  = threadIdx.x;
    int lane = tid & 63;
    int w    = tid >> 6;
    int wm   = (w & 1) * 32;       // wave m-offset
    int wn   = (w >> 1) * 64;      // wave n-offset
    int quad = lane >> 4;
    int c16  = lane & 15;

    f32x4 acc[2][4];
#pragma unroll
    for (int i = 0; i < 2; ++i)
#pragma unroll
        for (int j = 0; j < 4; ++j)
#pragma unroll
            for (int r = 0; r < 4; ++r) acc[i][j][r] = 0.0f;

    // staging coords
    int sr = tid >> 2;              // A row 0..63
    int sk = (tid & 3) * 8;         // A k-chunk
    int gm = m0 + sr;  if (gm > M - 1) gm = M - 1;
    const ushort_t* aptr = A + (size_t)gm * K + sk;
    int br0 = tid >> 2;             // B rows (2 chunks/thread)
    int bk0 = (tid & 3) * 8;
    int br1 = (256 + tid) >> 2;
    int bk1 = bk0;
    const ushort_t* bptr0 = Bt + (size_t)(n0 + br0) * K + bk0;
    const ushort_t* bptr1 = Bt + (size_t)(n0 + br1) * K + bk1;

    uint4 av  = *(const uint4*)(aptr);
    uint4 bv0 = *(const uint4*)(bptr0);
    uint4 bv1 = *(const uint4*)(bptr1);

    for (int k0 = 0; k0 < K; k0 += 32) {
        *(uint4*)&As[sr * LDT + sk]   = av;
        *(uint4*)&Bs[br0 * LDT + bk0] = bv0;
        *(uint4*)&Bs[br1 * LDT + bk1] = bv1;
        __syncthreads();

        short8x af0 = *(const short8x*)&As[(wm +      c16) * LDT + quad * 8];
        short8x af1 = *(const short8x*)&As[(wm + 16 + c16) * LDT + quad * 8];
        short8x bf[4];
#pragma unroll
        for (int nt = 0; nt < 4; ++nt)
            bf[nt] = *(const short8x*)&Bs[(wn + nt * 16 + c16) * LDT + quad * 8];

        // prefetch next iteration's tiles (in flight across MFMAs + barrier)
        if (k0 + 32 < K) {
            av  = *(const uint4*)(aptr  + k0 + 32);
            bv0 = *(const uint4*)(bptr0 + k0 + 32);
            bv1 = *(const uint4*)(bptr1 + k0 + 32);
        }

#pragma unroll
        for (int nt = 0; nt < 4; ++nt) {
            acc[0][nt] = __builtin_amdgcn_mfma_f32_16x16x32_bf16(af0, bf[nt], acc[0][nt], 0, 0, 0);
            acc[1][nt] = __builtin_amdgcn_mfma_f32_16x16x32_bf16(af1, bf[nt], acc[1][nt], 0, 0, 0);
        }
        __syncthreads();
    }

#pragma unroll
    for (int mt = 0; mt < 2; ++mt) {
#pragma unroll
        for (int r = 0; r < 4; ++r) {
            int row = m0 + wm + mt * 16 + quad * 4 + r;
            if (row < M) {
#pragma unroll
                for (int nt = 0; nt < 4; ++nt) {
                    int col = n0 + wn + nt * 16 + c16;
                    Cb[(size_t)row * 512 + col] = f2bf(acc[mt][nt][r]);
                }
            }
        }
    }
}

// ---------------------------------------------------------------------------
// logits: one wave per node (4 nodes/block). Lane l owns channels [8l, 8l+8).
// ---------------------------------------------------------------------------
template<int H>
__global__ __launch_bounds__(256) void logits_kernel(
    const uint4* __restrict__ xpb4,    // [node][64]
    const float* __restrict__ aS, const float* __restrict__ aD,
    float* __restrict__ s_log, float* __restrict__ d_log, int OUTC)
{
    int node = blockIdx.x * 4 + (threadIdx.x >> 6);
    if (node >= NNODES) return;
    int lane = threadIdx.x & 63;
    uint4 p = xpb4[(size_t)node * 64 + lane];
    float xv[8] = {bf_lo(p.x), bf_hi(p.x), bf_lo(p.y), bf_hi(p.y),
                   bf_lo(p.z), bf_hi(p.z), bf_lo(p.w), bf_hi(p.w)};
    int cbase = lane * 8;
    float sv = 0.f, dv = 0.f;
    if (cbase + 7 < OUTC) {
        float4 a0 = ((const float4*)aS)[lane * 2];
        float4 a1 = ((const float4*)aS)[lane * 2 + 1];
        float4 b0 = ((const float4*)aD)[lane * 2];
        float4 b1 = ((const float4*)aD)[lane * 2 + 1];
        sv = xv[0]*a0.x + xv[1]*a0.y + xv[2]*a0.z + xv[3]*a0.w
           + xv[4]*a1.x + xv[5]*a1.y + xv[6]*a1.z + xv[7]*a1.w;
        dv = xv[0]*b0.x + xv[1]*b0.y + xv[2]*b0.z + xv[3]*b0.w
           + xv[4]*b1.x + xv[5]*b1.y + xv[6]*b1.z + xv[7]*b1.w;
    } else {
#pragma unroll
        for (int k = 0; k < 8; ++k) {
            int c = cbase + k;
            if (c < OUTC) { sv += xv[k] * aS[c]; dv += xv[k] * aD[c]; }
        }
    }
    int grp = (H == 4) ? 16 : 64;
    for (int off = 1; off < grp; off <<= 1) {
        sv += __shfl_xor(sv, off);
        dv += __shfl_xor(dv, off);
    }
    if ((lane & (grp - 1)) == 0) {
        int h = (H == 4) ? (lane >> 4) : 0;
        s_log[node * H + h] = sv;
        d_log[node * H + h] = dv;
    }
}

// ---------------------------------------------------------------------------
// FUSED softmax+gather. Normalization is a trailing scalar:
//   out = (x_self + Σ_j w_j x_{src_j}) / (1 + Σ_j w_j),
//   w_j = exp(lrelu(s[src_j]+d[n]) - c0),  c0 = self logit (shift; w_self=1).
// Same per-edge load count as before (s_log[src] replaces ew[j]); adds one
// v_exp per edge-slice. Removes the 3 edge_softmax dispatches, the ew
// write+read (~10 MB/layer), and wself/zinv entirely.
// Slicing (proven R13): slice pinned per XCD pair, 2.56 MB L2-resident.
// ---------------------------------------------------------------------------
__device__ __forceinline__ void acc8(float* acc, uint4 q, float w) {
    acc[0] += w * bf_lo(q.x); acc[1] += w * bf_hi(q.x);
    acc[2] += w * bf_lo(q.y); acc[3] += w * bf_hi(q.y);
    acc[4] += w * bf_lo(q.z); acc[5] += w * bf_hi(q.z);
    acc[6] += w * bf_lo(q.w); acc[7] += w * bf_hi(q.w);
}

template<int H>
__global__ __launch_bounds__(256) void gather_fused_kernel(
    const uint4* __restrict__ xpb4,     // [node][64]
    const int* __restrict__ offsets, const int* __restrict__ esrc,
    const float* __restrict__ s_log,    // [node][H]
    const float* __restrict__ d_log,    // [node][H]
    const float* __restrict__ bias,     // [OUTC]
    float* __restrict__ out,            // [node][ldo]
    int OUTC, int ldo)
{
    int id = blockIdx.x;
    int xcd = id & 7;
    int slice = xcd >> 1;                       // 0..3 — pinned per XCD pair
    int sub2 = xcd & 1;
    int wv = threadIdx.x >> 6;
    int node = (id >> 3) * 8 + sub2 * 4 + wv;
    if (node >= NNODES) return;
    int lane = threadIdx.x & 63;
    int esub = lane >> 4;                       // edge subgroup 0..3
    int l16 = lane & 15;
    int h = (H == 4) ? slice : 0;
    int rowoff = slice * 16 + l16;              // uint4 index within 64-wide row

    // node-constant attention terms
    float dh = d_log[node * H + h];
    float c0 = lrelu(s_log[node * H + h] + dh); // self-loop logit = shift

    float acc[8];
    float z;
    if (esub == 0) {
        // self loop: w = exp(c0 - c0) = 1
        uint4 p = xpb4[(size_t)node * 64 + rowoff];
        acc[0] = bf_lo(p.x); acc[1] = bf_hi(p.x);
        acc[2] = bf_lo(p.y); acc[3] = bf_hi(p.y);
        acc[4] = bf_lo(p.z); acc[5] = bf_hi(p.z);
        acc[6] = bf_lo(p.w); acc[7] = bf_hi(p.w);
        z = 1.0f;
    } else {
#pragma unroll
        for (int k = 0; k < 8; ++k) acc[k] = 0.f;
        z = 0.f;
    }

    int e0 = offsets[node], e1 = offsets[node + 1];
    int j = e0 + esub;
    for (; j + 12 < e1; j += 16) {
        int s0 = esrc[j], s1 = esrc[j + 4], s2 = esrc[j + 8], s3 = esrc[j + 12];
        uint4 q0 = xpb4[(size_t)s0 * 64 + rowoff];
        uint4 q1 = xpb4[(size_t)s1 * 64 + rowoff];
        uint4 q2 = xpb4[(size_t)s2 * 64 + rowoff];
        uint4 q3 = xpb4[(size_t)s3 * 64 + rowoff];
        float w0 = __expf(lrelu(s_log[s0 * H + h] + dh) - c0);
        float w1 = __expf(lrelu(s_log[s1 * H + h] + dh) - c0);
        float w2 = __expf(lrelu(s_log[s2 * H + h] + dh) - c0);
        float w3 = __expf(lrelu(s_log[s3 * H + h] + dh) - c0);
        acc8(acc, q0, w0);
        acc8(acc, q1, w1);
        acc8(acc, q2, w2);
        acc8(acc, q3, w3);
        z += w0 + w1 + w2 + w3;
    }
    for (; j < e1; j += 4) {
        int s0 = esrc[j];
        uint4 q0 = xpb4[(size_t)s0 * 64 + rowoff];
        float w0 = __expf(lrelu(s_log[s0 * H + h] + dh) - c0);
        acc8(acc, q0, w0);
        z += w0;
    }

    // combine the 4 edge subgroups
#pragma unroll
    for (int k = 0; k < 8; ++k) {
        acc[k] += __shfl_xor(acc[k], 16);
        acc[k] += __shfl_xor(acc[k], 32);
    }
    z += __shfl_xor(z, 16);
    z += __shfl_xor(z, 32);

    if (esub == 0) {
        float zi = 1.0f / z;
        int cbase = slice * 128 + l16 * 8;
        size_t ob = (size_t)node * ldo + cbase;
        if (cbase + 7 < OUTC) {
            float4 o0 = make_float4(acc[0] * zi + bias[cbase + 0], acc[1] * zi + bias[cbase + 1],
                                    acc[2] * zi + bias[cbase + 2], acc[3] * zi + bias[cbase + 3]);
            float4 o1 = make_float4(acc[4] * zi + bias[cbase + 4], acc[5] * zi + bias[cbase + 5],
                                    acc[6] * zi + bias[cbase + 6], acc[7] * zi + bias[cbase + 7]);
            *(float4*)(out + ob) = o0;
            *(float4*)(out + ob + 4) = o1;
        } else {
#pragma unroll
            for (int k = 0; k < 8; ++k) {
                int c = cbase + k;
                if (c < OUTC) out[ob + k] = acc[k] * zi + bias[c];
            }
        }
    }
}

// ---------------------------------------------------------------------------
// BatchNorm: stats (64-block partials) -> tiny finalize -> wide apply+pack.
// ---------------------------------------------------------------------------
__global__ __launch_bounds__(512) void bn_stats_kernel(const float* __restrict__ h,
                                                       float* __restrict__ psum,
                                                       float* __restrict__ psumsq) {
    int c = threadIdx.x;  // 512
    int b = blockIdx.x;   // 64
    float sm = 0.f, sq = 0.f;
    for (int r = b; r < NNODES; r += 64) {
        float v = h[(size_t)r * 512 + c];
        sm += v;
        sq += v * v;
    }
    psum[b * 512 + c] = sm;
    psumsq[b * 512 + c] = sq;
}

__global__ __launch_bounds__(512) void bn_finalize_kernel(const float* __restrict__ psum,
                                                          const float* __restrict__ psumsq,
                                                          const float* __restrict__ gamma,
                                                          const float* __restrict__ beta,
                                                          float* __restrict__ scale,
                                                          float* __restrict__ shift) {
    int c = threadIdx.x;
    float sm = 0.f, sq = 0.f;
    for (int b = 0; b < 64; ++b) {
        sm += psum[b * 512 + c];
        sq += psumsq[b * 512 + c];
    }
    const float invN = 1.0f / (float)NNODES;
    float mu = sm * invN;
    float var = sq * invN - mu * mu;
    float sc = gamma[c] * rsqrtf(var + BN_EPS);
    scale[c] = sc;
    shift[c] = beta[c] - mu * sc;
}

__global__ __launch_bounds__(256) void bn_apply_kernel(const float* __restrict__ h,
                                                       const float* __restrict__ scale,
                                                       const float* __restrict__ shift,
                                                       uint_t* __restrict__ hbf) {
    int t = threadIdx.x, b = blockIdx.x;   // grid = 256
    int c0 = t * 2, c1 = c0 + 1;
    float sc0 = scale[c0], sc1 = scale[c1];
    float sh0 = shift[c0], sh1 = shift[c1];
    for (int r = b; r < NNODES; r += 256) {
        float2 hv = ((const float2*)(h + (size_t)r * 512))[t];
        float v0 = hv.x * sc0 + sh0;
        float v1 = hv.y * sc1 + sh1;
        v0 = (v0 > 0.f) ? v0 : (__expf(v0) - 1.0f);
        v1 = (v1 > 0.f) ? v1 : (__expf(v1) - 1.0f);
        hbf[r * 256 + t] = ((uint_t)f2bf(v1) << 16) | (uint_t)f2bf(v0);
    }
}

// ---------------------------------------------------------------------------
// launch — 21 dispatches
// ---------------------------------------------------------------------------
extern "C" void kernel_launch(void* const* d_in, const int* in_sizes, int n_in,
                              void* d_out, int out_size, void* d_ws, size_t ws_size,
                              hipStream_t stream) {
    const float* x      = (const float*)d_in[0];
    const int*   ei     = (const int*)d_in[1];
    const float* W1     = (const float*)d_in[2];
    const float* a_src1 = (const float*)d_in[3];
    const float* a_dst1 = (const float*)d_in[4];
    const float* b1     = (const float*)d_in[5];
    const float* g1     = (const float*)d_in[6];
    const float* be1    = (const float*)d_in[7];
    const float* W2     = (const float*)d_in[8];
    const float* a_src2 = (const float*)d_in[9];
    const float* a_dst2 = (const float*)d_in[10];
    const float* b2     = (const float*)d_in[11];
    const float* g2     = (const float*)d_in[12];
    const float* be2    = (const float*)d_in[13];
    const float* W3     = (const float*)d_in[14];
    const float* a_src3 = (const float*)d_in[15];
    const float* a_dst3 = (const float*)d_in[16];
    const float* b3     = (const float*)d_in[17];
    float* out = (float*)d_out;

    const int* e_src = ei;           // edge_index[0]
    const int* e_dst = ei + NEDGES;  // edge_index[1]

    // ---- workspace layout ----
    char* w = (char*)d_ws;
    ushort_t* x_bf = (ushort_t*)w;
    float*    hbuf = (float*)w;                               // alias after L1 GEMM
    w += (size_t)NNODES * INF_ * sizeof(ushort_t);            // 25.6 MB
    uint_t* xpb = (uint_t*)w;  w += (size_t)NNODES * HC_ * sizeof(ushort_t);
    uint_t* hbf = (uint_t*)w;  w += (size_t)NNODES * HC_ * sizeof(ushort_t);
    ushort_t* Wt1 = (ushort_t*)w; w += (size_t)HC_ * INF_ * sizeof(ushort_t);
    ushort_t* Wt2 = (ushort_t*)w; w += (size_t)HC_ * HC_ * sizeof(ushort_t);
    ushort_t* Wt3 = (ushort_t*)w; w += (size_t)HC_ * HC_ * sizeof(ushort_t);
    int* counts  = (int*)w;    w += NNODES * sizeof(int);
    float* s_log = (float*)w;  w += NNODES * HEADS_ * sizeof(float);
    float* d_log = (float*)w;  w += NNODES * HEADS_ * sizeof(float);
    float* bnscale = (float*)w; w += HC_ * sizeof(float);
    float* bnshift = (float*)w; w += HC_ * sizeof(float);
    float* psum  = (float*)w;  w += 64 * HC_ * sizeof(float);
    float* psumsq= (float*)w;  w += 64 * HC_ * sizeof(float);
    int* offsets = (int*)w;    w += (NNODES + 1) * sizeof(int);
    int* cursor  = (int*)w;    w += NNODES * sizeof(int);
    int* esrc    = (int*)w;    w += NEDGES * sizeof(int);
    int* bsum    = (int*)w;    w += 64 * sizeof(int);

    dim3 gg(HC_ / 128, (NNODES + 63) / 64);          // (4, 157) — 64x128 tile
    const int lgGrid = (NNODES + 3) / 4;             // 2500 (logits)
    const int gaGrid = ((NNODES + 7) / 8) * 8;       // 10000 (sliced gather)
    const int scanBlocks = (NNODES + 255) / 256;     // 40

    zero_kernel<<<32, 256, 0, stream>>>((float*)counts, NNODES);
    count_kernel<<<(NEDGES + 255) / 256, 256, 0, stream>>>(e_dst, counts, NEDGES);
    scan1_kernel<<<scanBlocks, 256, 0, stream>>>(counts, offsets, bsum, NNODES);
    scan3b_kernel<<<scanBlocks, 256, 0, stream>>>(offsets, cursor, bsum, scanBlocks, NNODES);
    scatter_kernel<<<(NEDGES + 255) / 256, 256, 0, stream>>>(e_src, e_dst, cursor, esrc, NEDGES);
    {
        int TOT = CVX + CN1 + CN2 + CN3;
        convall_kernel<<<(TOT + 255) / 256, 256, 0, stream>>>(x, W1, W2, W3, x_bf, Wt1, Wt2, Wt3);
    }

    // ---- Layer 1 ----
    gemm_kernel<<<gg, 256, 0, stream>>>(x_bf, Wt1, (ushort_t*)xpb, NNODES, INF_);
    logits_kernel<HEADS_><<<lgGrid, 256, 0, stream>>>((const uint4*)xpb, a_src1, a_dst1, s_log, d_log, HC_);
    gather_fused_kernel<HEADS_><<<gaGrid, 256, 0, stream>>>((const uint4*)xpb, offsets, esrc,
        s_log, d_log, b1, hbuf, HC_, HC_);
    bn_stats_kernel<<<64, 512, 0, stream>>>(hbuf, psum, psumsq);
    bn_finalize_kernel<<<1, 512, 0, stream>>>(psum, psumsq, g1, be1, bnscale, bnshift);
    bn_apply_kernel<<<256, 256, 0, stream>>>(hbuf, bnscale, bnshift, hbf);

    // ---- Layer 2 ----
    gemm_kernel<<<gg, 256, 0, stream>>>((const ushort_t*)hbf, Wt2, (ushort_t*)xpb, NNODES, HC_);
    logits_kernel<HEADS_><<<lgGrid, 256, 0, stream>>>((const uint4*)xpb, a_src2, a_dst2, s_log, d_log, HC_);
    gather_fused_kernel<HEADS_><<<gaGrid, 256, 0, stream>>>((const uint4*)xpb, offsets, esrc,
        s_log, d_log, b2, hbuf, HC_, HC_);
    bn_stats_kernel<<<64, 512, 0, stream>>>(hbuf, psum, psumsq);
    bn_finalize_kernel<<<1, 512, 0, stream>>>(psum, psumsq, g2, be2, bnscale, bnshift);
    bn_apply_kernel<<<256, 256, 0, stream>>>(hbuf, bnscale, bnshift, hbf);

    // ---- Layer 3 (H=1, N=500) ----
    gemm_kernel<<<gg, 256, 0, stream>>>((const ushort_t*)hbf, Wt3, (ushort_t*)xpb, NNODES, HC_);
    logits_kernel<1><<<lgGrid, 256, 0, stream>>>((const uint4*)xpb, a_src3, a_dst3, s_log, d_log, OUTF_);
    gather_fused_kernel<1><<<gaGrid, 256, 0, stream>>>((const uint4*)xpb, offsets, esrc,
        s_log, d_log, b3, out, OUTF_, OUTF_);
}